// Round 1
// baseline (372.075 us; speedup 1.0000x reference)
//
#include <hip/hip_runtime.h>
#include <math.h>

typedef __attribute__((ext_vector_type(4))) float f32x4;
typedef _Float16 f16;
typedef __attribute__((ext_vector_type(8))) _Float16 f16x8;

// Problem constants (DeepSeek-V3 gate: hidden (4,2048,7168), 256 experts)
constexpr int H       = 7168;
constexpr int E       = 256;
constexpr int T_TOTAL = 8192;     // 4*2048 tokens

constexpr int KSPLIT  = 4;
constexpr int K_SLICE = H / KSPLIT;    // 1792
constexpr int NCH     = K_SLICE / 64;  // 28 chunks of BK=64
constexpr int NPAIR   = NCH / 2;       // 14 barrier periods (BK=128 per sync)
constexpr int MT      = 64;            // tokens per GEMM block (4 mtiles)

constexpr int N_GROUP    = 8;
constexpr int TOPK_GROUP = 4;
constexpr int TOP_K      = 8;

constexpr size_t SCORES_OFF = 8u * 1024 * 1024;   // ws: wf at 0 (7.34MB), scores at 8MB

// ---------------------------------------------------------------------------
// Kernel 1: split w (fp32) into f16 hi/lo in MFMA B-fragment order:
//   wf[((kc*16 + ntile)*2 + s)*512 + lane*8 + j]
//   kc = h>>5, ntile = e>>4, s = 0(hi)/1(lo), lane = ((h>>3)&3)<<4 | (e&15)
// ---------------------------------------------------------------------------
__global__ __launch_bounds__(64) void pack_w_kernel(const float* __restrict__ w,
                                                    f16* __restrict__ wf)
{
    const int l  = threadIdx.x;
    const int nt = blockIdx.x & 15;
    const int kc = blockIdx.x >> 4;
    const int e  = nt * 16 + (l & 15);
    const int h  = kc * 32 + (l >> 4) * 8;
    const float* src = &w[(size_t)e * H + h];
    f32x4 v0 = *reinterpret_cast<const f32x4*>(src);
    f32x4 v1 = *reinterpret_cast<const f32x4*>(src + 4);
    float v[8] = {v0[0], v0[1], v0[2], v0[3], v1[0], v1[1], v1[2], v1[3]};
    f16x8 hi, lo;
    #pragma unroll
    for (int j = 0; j < 8; ++j) {
        f16 h16 = (f16)v[j];
        hi[j] = h16;
        lo[j] = (f16)(v[j] - (float)h16);
    }
    const size_t base = (((size_t)kc * 16 + nt) * 2) * 512 + (size_t)l * 8;
    *reinterpret_cast<f16x8*>(&wf[base])       = hi;
    *reinterpret_cast<f16x8*>(&wf[base + 512]) = lo;
}

// ---------------------------------------------------------------------------
// Kernel 2: router GEMM, f16-split MFMA (acc += Ahi*Bhi + Ahi*Blo + Alo*Bhi).
// Grid: 512 = 64 M-tiles x 4 K-slices (2 blocks/CU); ksl = bid&3 pins one
// 1.84MB wf slice per XCD -> L2-resident weights.
// Block: 512 thr = 8 waves; block tile 64m x 256n; wave tile 64m x 32n.
// This revision vs previous:
//  - 2 chunks (128 k) per sync: 14 barriers instead of 28.
//  - barrier = asm lgkmcnt(0) + raw s_barrier (NO vmcnt drain): x/B global
//    prefetch stays in flight across the barrier. Safe here because staging
//    is reg->ds_write (not global_load_lds); all global loads are consumed
//    through compiler-tracked register deps.
//  - mfma_step loads A per-mtile (8 transient VGPRs, not a[4][2]=32): peak
//    VGPR under the 128 cap of __launch_bounds__(512,4) -> no spill.
//    Per-accumulator MFMA order unchanged (hihi, hilo, lohi per 32-k step)
//    -> bit-identical numerics to the verified kernel.
//  - s_setprio(1) around the MFMA region.
// ---------------------------------------------------------------------------
__global__ __launch_bounds__(512, 4) void gemm_kernel(
    const float* __restrict__ x,      // [T_TOTAL, H] fp32
    const f16*   __restrict__ wf,     // packed B-fragments
    float* __restrict__ scores)       // [T_TOTAL][KSPLIT][E] partial logits
{
    // [buf][half][mtile 0..3][ks 0..1][s 0..1][lane 0..63][j 0..7] = 64 KB
    __shared__ __align__(16) f16 x_lds[2][2][4 * 2 * 2 * 512];

    const int tid  = threadIdx.x;
    const int lane = tid & 63;
    const int wn   = tid >> 6;     // wave 0..7: experts wn*32 .. +31

    const int bid = blockIdx.x;
    const int ksl = bid & 3;
    const int mb  = bid >> 2;      // 0..63
    const int t0  = mb * MT;
    const int k0  = ksl * K_SLICE;
    const int kc0 = k0 >> 5;       // first K-chunk-of-32 index

    // x loader: tid -> (mtile, ks, lane); 8 floats per thread per chunk
    const int lmt = (tid >> 6) & 3;
    const int lks = tid >> 8;                 // 0..1
    const float* xrow = &x[(size_t)(t0 + lmt * 16 + (lane & 15)) * H
                           + k0 + lks * 32 + (lane >> 4) * 8];

    const int lm = lane & 15;
    const int kq = lane >> 4;

    f32x4 acc[4][2];
    #pragma unroll
    for (int mt = 0; mt < 4; ++mt)
        #pragma unroll
        for (int nt = 0; nt < 2; ++nt)
            acc[mt][nt] = (f32x4){0.f, 0.f, 0.f, 0.f};

    // stage this thread's 8 floats as hi/lo fragments into LDS
    auto stage = [&](int bu, int half, f32x4 v0, f32x4 v1) {
        float v[8] = {v0[0], v0[1], v0[2], v0[3], v1[0], v1[1], v1[2], v1[3]};
        f16x8 hi, lo;
        #pragma unroll
        for (int j = 0; j < 8; ++j) {
            f16 h16 = (f16)v[j];
            hi[j] = h16;
            lo[j] = (f16)(v[j] - (float)h16);
        }
        f16* base = &x_lds[bu][half][((lmt * 2 + lks) * 2) * 512 + lane * 8];
        *reinterpret_cast<f16x8*>(base)       = hi;
        *reinterpret_cast<f16x8*>(base + 512) = lo;
    };

    auto load_b = [&](f16x8 (&b)[2][2], int kc) {
        #pragma unroll
        for (int nt = 0; nt < 2; ++nt)
            #pragma unroll
            for (int s = 0; s < 2; ++s)
                b[nt][s] = *reinterpret_cast<const f16x8*>(
                    &wf[(((size_t)kc * 16 + wn * 2 + nt) * 2 + s) * 512 + lane * 8]);
    };

    // per-mtile A fragments: 8 live VGPRs instead of 32; per-acc order is
    // hihi, hilo, lohi within each 32-k step (identical to verified kernel)
    auto mfma_step = [&](const f16x8 (&b)[2][2], int bu, int half, int ks) {
        #pragma unroll
        for (int mt = 0; mt < 4; ++mt) {
            const f16* ap = &x_lds[bu][half][((mt * 2 + ks) * 2) * 512 + lane * 8];
            f16x8 ahi = *reinterpret_cast<const f16x8*>(ap);
            f16x8 alo = *reinterpret_cast<const f16x8*>(ap + 512);
            acc[mt][0] = __builtin_amdgcn_mfma_f32_16x16x32_f16(ahi, b[0][0], acc[mt][0], 0, 0, 0);
            acc[mt][1] = __builtin_amdgcn_mfma_f32_16x16x32_f16(ahi, b[1][0], acc[mt][1], 0, 0, 0);
            acc[mt][0] = __builtin_amdgcn_mfma_f32_16x16x32_f16(ahi, b[0][1], acc[mt][0], 0, 0, 0);
            acc[mt][1] = __builtin_amdgcn_mfma_f32_16x16x32_f16(ahi, b[1][1], acc[mt][1], 0, 0, 0);
            acc[mt][0] = __builtin_amdgcn_mfma_f32_16x16x32_f16(alo, b[0][0], acc[mt][0], 0, 0, 0);
            acc[mt][1] = __builtin_amdgcn_mfma_f32_16x16x32_f16(alo, b[1][0], acc[mt][1], 0, 0, 0);
        }
    };

    f16x8 b0[2][2], b1[2][2];

    // prologue: stage chunks 0,1 into buf 0; preload first B step
    {
        f32x4 v0 = *reinterpret_cast<const f32x4*>(xrow);
        f32x4 v1 = *reinterpret_cast<const f32x4*>(xrow + 4);
        f32x4 v2 = *reinterpret_cast<const f32x4*>(xrow + 64);
        f32x4 v3 = *reinterpret_cast<const f32x4*>(xrow + 68);
        stage(0, 0, v0, v1);
        stage(0, 1, v2, v3);
    }
    load_b(b0, kc0);
    __syncthreads();

    for (int i = 0; i < NPAIR; ++i) {
        const int buf   = i & 1;
        const int kbase = kc0 + i * 4;
        const bool last = (i + 1 == NPAIR);

        // prefetch next pair of x chunks into registers (HBM latency hides
        // under ~2 chunks of MFMA; loads may also span the barrier now)
        f32x4 nva0, nva1, nvb0, nvb1;
        if (!last) {
            const float* nx = xrow + (2 * i + 2) * 64;
            nva0 = *reinterpret_cast<const f32x4*>(nx);
            nva1 = *reinterpret_cast<const f32x4*>(nx + 4);
            nvb0 = *reinterpret_cast<const f32x4*>(nx + 64);
            nvb1 = *reinterpret_cast<const f32x4*>(nx + 68);
        }

        // B register pipeline across the 4 K-steps of this pair
        load_b(b1, kbase + 1);
        __builtin_amdgcn_s_setprio(1);
        mfma_step(b0, buf, 0, 0);
        load_b(b0, kbase + 2);
        mfma_step(b1, buf, 0, 1);
        load_b(b1, kbase + 3);
        mfma_step(b0, buf, 1, 0);
        load_b(b0, last ? kc0 : (kbase + 4));   // next pair's first step
        mfma_step(b1, buf, 1, 1);
        __builtin_amdgcn_s_setprio(0);

        if (!last) {
            stage(buf ^ 1, 0, nva0, nva1);
            stage(buf ^ 1, 1, nvb0, nvb1);
            // lgkmcnt-only barrier: drain ds_write/ds_read, leave global
            // prefetch (vmcnt) in flight across the sync.
            asm volatile("s_waitcnt lgkmcnt(0)" ::: "memory");
            __builtin_amdgcn_s_barrier();
            asm volatile("" ::: "memory");
        }
    }

    // epilogue: raw partial logits, layout [T][KSPLIT][E]
    // C/D: col(expert)=lane&15, row(token)=(lane>>4)*4+reg
    #pragma unroll
    for (int mt = 0; mt < 4; ++mt)
        #pragma unroll
        for (int nt = 0; nt < 2; ++nt)
            #pragma unroll
            for (int r = 0; r < 4; ++r) {
                const int tok = mt * 16 + kq * 4 + r;
                const int e   = wn * 32 + nt * 16 + lm;
                scores[(((size_t)(t0 + tok)) * KSPLIT + ksl) * E + e] = acc[mt][nt][r];
            }
}

// ---------------------------------------------------------------------------
// Kernel 3: reduce K-split partials, sigmoid, grouped top-k gating.
// ONE TOKEN PER WAVE, fully register-resident (unchanged, verified).
// ---------------------------------------------------------------------------
__global__ __launch_bounds__(256) void gate_kernel(
    const float* __restrict__ scores,  // [T_TOTAL][KSPLIT][E]
    const float* __restrict__ bias,    // [E]
    float* __restrict__ out)           // [T*8 idx floats][T*8 weight floats]
{
    const int lane = threadIdx.x & 63;
    const int wv   = threadIdx.x >> 6;            // 0..3
    const int t    = blockIdx.x * 4 + wv;

    // reduce K-split partials: lane l covers experts 4l..4l+3
    const float* p = &scores[(size_t)t * (KSPLIT * E) + lane * 4];
    f32x4 s = (f32x4){0.f, 0.f, 0.f, 0.f};
    #pragma unroll
    for (int k = 0; k < KSPLIT; ++k)
        s += *reinterpret_cast<const f32x4*>(p + k * E);
    f32x4 bi = *reinterpret_cast<const f32x4*>(&bias[lane * 4]);

    float sig[4], bsc[4];
    #pragma unroll
    for (int j = 0; j < 4; ++j) {
        sig[j] = 1.0f / (1.0f + expf(-s[j]));
        bsc[j] = sig[j] + bi[j];
    }

    // ---- group score = sum of top-2 biased scores (group = 8 lanes) ----
    float h01 = fmaxf(bsc[0], bsc[1]), l01 = fminf(bsc[0], bsc[1]);
    float h23 = fmaxf(bsc[2], bsc[3]), l23 = fminf(bsc[2], bsc[3]);
    float m1 = fmaxf(h01, h23);
    float m2 = fmaxf(fminf(h01, h23), fmaxf(l01, l23));
    #pragma unroll
    for (int d = 1; d < 8; d <<= 1) {
        float om1 = __shfl_xor(m1, d);
        float om2 = __shfl_xor(m2, d);
        float nm1 = fmaxf(m1, om1);
        float nm2 = fmaxf(fminf(m1, om1), fmaxf(m2, om2));
        m1 = nm1; m2 = nm2;
    }
    const float gs  = m1 + m2;
    const int   gid = lane >> 3;

    // ---- top-4 groups by rank count (ties -> lowest group index) ----
    int cnt = 0;
    #pragma unroll
    for (int j = 0; j < N_GROUP; ++j) {
        float gsj = __shfl(gs, j * 8);
        cnt += (gsj > gs || (gsj == gs && j < gid)) ? 1 : 0;
    }
    const bool sel = (cnt < TOPK_GROUP);

    float mb[4];
    #pragma unroll
    for (int j = 0; j < 4; ++j) mb[j] = sel ? bsc[j] : -INFINITY;

    // ---- top-8 experts: 8 wave-argmax rounds, all-register ----
    float wsum = 0.f;
    f32x4 iv0, iv1, wv0, wv1;
    #pragma unroll
    for (int r = 0; r < TOP_K; ++r) {
        float v = mb[0]; int li = 0;
        if (mb[1] > v) { v = mb[1]; li = 1; }
        if (mb[2] > v) { v = mb[2]; li = 2; }
        if (mb[3] > v) { v = mb[3]; li = 3; }
        int ei = lane * 4 + li;
        #pragma unroll
        for (int d = 1; d < 64; d <<= 1) {
            float ov = __shfl_xor(v, d);
            int   oi = __shfl_xor(ei, d);
            if (ov > v || (ov == v && oi < ei)) { v = ov; ei = oi; }
        }
        // ei now uniform = argmax with lowest-index tie-break
        const int sub = ei & 3, owner = ei >> 2;
        const float svl = (sub & 2) ? ((sub & 1) ? sig[3] : sig[2])
                                    : ((sub & 1) ? sig[1] : sig[0]);
        const float wr = __shfl(svl, owner);      // UNBIASED score
        #pragma unroll
        for (int j = 0; j < 4; ++j)               // mask winner (static idx)
            if (lane == owner && j == sub) mb[j] = -INFINITY;
        wsum += wr;
        if (r < 4) { iv0[r] = (float)ei;     wv0[r] = wr; }
        else       { iv1[r - 4] = (float)ei; wv1[r - 4] = wr; }
    }

    const float scale = 2.5f / wsum;
    #pragma unroll
    for (int j = 0; j < 4; ++j) { wv0[j] *= scale; wv1[j] *= scale; }

    if (lane == 0) {
        float* oi_ = out + (size_t)t * TOP_K;
        float* ow_ = out + (size_t)T_TOTAL * TOP_K + (size_t)t * TOP_K;
        *reinterpret_cast<f32x4*>(oi_)     = iv0;
        *reinterpret_cast<f32x4*>(oi_ + 4) = iv1;
        *reinterpret_cast<f32x4*>(ow_)     = wv0;
        *reinterpret_cast<f32x4*>(ow_ + 4) = wv1;
    }
}

extern "C" void kernel_launch(void* const* d_in, const int* in_sizes, int n_in,
                              void* d_out, int out_size, void* d_ws, size_t ws_size,
                              hipStream_t stream) {
    const float* x    = (const float*)d_in[0];
    const float* w    = (const float*)d_in[1];
    const float* bias = (const float*)d_in[2];
    float* out = (float*)d_out;

    f16*   wf     = (f16*)d_ws;
    float* scores = (float*)((char*)d_ws + SCORES_OFF);   // 33.6 MB partials

    hipLaunchKernelGGL(pack_w_kernel, dim3((H / 32) * 16), dim3(64), 0, stream, w, wf);
    hipLaunchKernelGGL(gemm_kernel, dim3((T_TOTAL / MT) * KSPLIT), dim3(512), 0, stream,
                       x, wf, scores);
    hipLaunchKernelGGL(gate_kernel, dim3(T_TOTAL / 4), dim3(256), 0, stream,
                       scores, bias, out);
}